// Round 1
// baseline (285.769 us; speedup 1.0000x reference)
//
#include <hip/hip_runtime.h>

#define EMB 128

// Write start offsets per user: start[u] = first behavior index with
// behavior_user_ids[j] >= u. Valid because behavior_user_ids is sorted.
// Covers all u in [0, n_users] exactly once (gap users get the boundary).
__global__ __launch_bounds__(256) void boundary_kernel(
    const int* __restrict__ beh_user, int* __restrict__ start,
    int n_beh, int n_users)
{
    int j = blockIdx.x * 256 + threadIdx.x;
    if (j >= n_beh) return;
    int cur  = beh_user[j];
    int prev = (j == 0) ? -1 : beh_user[j - 1];
    if (cur != prev) {
        for (int u = prev + 1; u <= cur; ++u) start[u] = j;
    }
    if (j == n_beh - 1) {
        for (int u = cur + 1; u <= n_users; ++u) start[u] = n_beh;
    }
}

// One wave (64 lanes) per user; lane L owns dims [2L, 2L+1] (float2).
// 4 waves per block. Block-level LDS reduction when all 4 users share a
// group (common: user_group_ids sorted, ~32 users/group).
__global__ __launch_bounds__(256) void per_user_kernel(
    const int*   __restrict__ user_ids,
    const int*   __restrict__ group_ids,
    const int*   __restrict__ beh_item,
    const float* __restrict__ beh_cnt,
    const int*   __restrict__ beh_user,   // fallback binary search only
    const float* __restrict__ user_table,
    const float* __restrict__ item_table,
    const int*   __restrict__ start,      // may be null -> binary search
    float*       __restrict__ out,
    int n_users, int n_beh)
{
    const int lane = threadIdx.x & 63;
    const int wave = threadIdx.x >> 6;
    const int user = blockIdx.x * 4 + wave;

    __shared__ float lds_acc[EMB];
    __shared__ int   lds_grp[4];
    if (threadIdx.x < EMB) lds_acc[threadIdx.x] = 0.0f;

    float2 acc = make_float2(0.0f, 0.0f);
    int g = -1;

    if (user < n_users) {
        int s, e;
        if (start) {
            s = start[user];
            e = start[user + 1];
        } else {
            int lo = 0, hi = n_beh;
            while (lo < hi) { int m = (lo + hi) >> 1; if (beh_user[m] < user) lo = m + 1; else hi = m; }
            s = lo;
            hi = n_beh;
            while (lo < hi) { int m = (lo + hi) >> 1; if (beh_user[m] <= user) lo = m + 1; else hi = m; }
            e = lo;
        }

        const float* itp = item_table + lane * 2;
        float2 a0 = make_float2(0.f, 0.f), a1 = a0, a2 = a0, a3 = a0;
        int j = s;
        for (; j + 4 <= e; j += 4) {
            int   b0 = beh_item[j],     b1 = beh_item[j + 1];
            int   b2 = beh_item[j + 2], b3 = beh_item[j + 3];
            float c0 = beh_cnt[j],      c1 = beh_cnt[j + 1];
            float c2 = beh_cnt[j + 2],  c3 = beh_cnt[j + 3];
            float2 v0 = *(const float2*)(itp + (size_t)b0 * EMB);
            float2 v1 = *(const float2*)(itp + (size_t)b1 * EMB);
            float2 v2 = *(const float2*)(itp + (size_t)b2 * EMB);
            float2 v3 = *(const float2*)(itp + (size_t)b3 * EMB);
            a0.x = fmaf(v0.x, c0, a0.x); a0.y = fmaf(v0.y, c0, a0.y);
            a1.x = fmaf(v1.x, c1, a1.x); a1.y = fmaf(v1.y, c1, a1.y);
            a2.x = fmaf(v2.x, c2, a2.x); a2.y = fmaf(v2.y, c2, a2.y);
            a3.x = fmaf(v3.x, c3, a3.x); a3.y = fmaf(v3.y, c3, a3.y);
        }
        for (; j < e; ++j) {
            int   b = beh_item[j];
            float c = beh_cnt[j];
            float2 v = *(const float2*)(itp + (size_t)b * EMB);
            a0.x = fmaf(v.x, c, a0.x); a0.y = fmaf(v.y, c, a0.y);
        }
        acc.x = (a0.x + a1.x) + (a2.x + a3.x);
        acc.y = (a0.y + a1.y) + (a2.y + a3.y);

        int uid = user_ids[user];
        float2 ue = make_float2(0.f, 0.f);
        if (uid != 0) ue = *(const float2*)(user_table + (size_t)uid * EMB + lane * 2);
        acc.x *= ue.x;
        acc.y *= ue.y;

        g = group_ids[user];
    }

    if (lane == 0) lds_grp[wave] = g;
    __syncthreads();

    int g0 = lds_grp[0];
    bool same = (g0 >= 0) && (lds_grp[1] == g0) && (lds_grp[2] == g0) && (lds_grp[3] == g0);
    if (same) {
        // block-uniform branch: all threads take it together
        atomicAdd(&lds_acc[lane * 2],     acc.x);
        atomicAdd(&lds_acc[lane * 2 + 1], acc.y);
        __syncthreads();
        if (wave == 0) {
            atomicAdd(&out[(size_t)g0 * EMB + lane * 2],     lds_acc[lane * 2]);
            atomicAdd(&out[(size_t)g0 * EMB + lane * 2 + 1], lds_acc[lane * 2 + 1]);
        }
    } else if (g >= 0) {
        atomicAdd(&out[(size_t)g * EMB + lane * 2],     acc.x);
        atomicAdd(&out[(size_t)g * EMB + lane * 2 + 1], acc.y);
    }
}

extern "C" void kernel_launch(void* const* d_in, const int* in_sizes, int n_in,
                              void* d_out, int out_size, void* d_ws, size_t ws_size,
                              hipStream_t stream) {
    const int*   user_ids   = (const int*)  d_in[0];
    const int*   group_ids  = (const int*)  d_in[1];
    const int*   beh_item   = (const int*)  d_in[2];
    const float* beh_cnt    = (const float*)d_in[3];
    const int*   beh_user   = (const int*)  d_in[4];
    const float* user_table = (const float*)d_in[5];
    const float* item_table = (const float*)d_in[6];

    const int n_users = in_sizes[0];
    const int n_beh   = in_sizes[2];

    float* out = (float*)d_out;
    hipMemsetAsync(out, 0, (size_t)out_size * sizeof(float), stream);

    int* start = nullptr;
    if (ws_size >= (size_t)(n_users + 1) * sizeof(int)) {
        start = (int*)d_ws;
        int bblocks = (n_beh + 255) / 256;
        boundary_kernel<<<bblocks, 256, 0, stream>>>(beh_user, start, n_beh, n_users);
    }

    int ublocks = (n_users + 3) / 4;
    per_user_kernel<<<ublocks, 256, 0, stream>>>(
        user_ids, group_ids, beh_item, beh_cnt, beh_user,
        user_table, item_table, start, out, n_users, n_beh);
}

// Round 2
// 246.528 us; speedup vs baseline: 1.1592x; 1.1592x over previous
//
#include <hip/hip_runtime.h>
#include <hip/hip_fp16.h>

#define EMB 128

// fp32 -> fp16 table conversion; 8 elements per thread.
__global__ __launch_bounds__(256) void convert_kernel(
    const float* __restrict__ src, __half* __restrict__ dst, int n8)
{
    int t = blockIdx.x * 256 + threadIdx.x;
    if (t >= n8) return;
    const float4* s = (const float4*)src + (size_t)t * 2;
    float4 f0 = s[0];
    float4 f1 = s[1];
    union { __half h[8]; uint4 u; } pk;
    pk.h[0] = __float2half_rn(f0.x);
    pk.h[1] = __float2half_rn(f0.y);
    pk.h[2] = __float2half_rn(f0.z);
    pk.h[3] = __float2half_rn(f0.w);
    pk.h[4] = __float2half_rn(f1.x);
    pk.h[5] = __float2half_rn(f1.y);
    pk.h[6] = __float2half_rn(f1.z);
    pk.h[7] = __float2half_rn(f1.w);
    ((uint4*)dst)[t] = pk.u;
}

// start[u] = first behavior index with behavior_user_ids[j] >= u.
// Valid because behavior_user_ids is sorted.
__global__ __launch_bounds__(256) void boundary_kernel(
    const int* __restrict__ beh_user, int* __restrict__ start,
    int n_beh, int n_users)
{
    int j = blockIdx.x * 256 + threadIdx.x;
    if (j >= n_beh) return;
    int cur  = beh_user[j];
    int prev = (j == 0) ? -1 : beh_user[j - 1];
    if (cur != prev) {
        for (int u = prev + 1; u <= cur; ++u) start[u] = j;
    }
    if (j == n_beh - 1) {
        for (int u = cur + 1; u <= n_users; ++u) start[u] = n_beh;
    }
}

// One wave (64 lanes) per user; lane L owns dims [2L, 2L+1].
// 4 waves per block; LDS reduction when all 4 users share a group.
template<bool FP16>
__global__ __launch_bounds__(256) void per_user_kernel(
    const int*   __restrict__ user_ids,
    const int*   __restrict__ group_ids,
    const int*   __restrict__ beh_item,
    const float* __restrict__ beh_cnt,
    const int*   __restrict__ beh_user,   // binary-search fallback only
    const float* __restrict__ user_table,
    const float* __restrict__ item_f32,
    const __half* __restrict__ item_f16,
    const int*   __restrict__ start,      // may be null -> binary search
    float*       __restrict__ out,
    int n_users, int n_beh)
{
    const int lane = threadIdx.x & 63;
    const int wave = threadIdx.x >> 6;
    const int user = blockIdx.x * 4 + wave;

    __shared__ float lds_acc[EMB];
    __shared__ int   lds_grp[4];
    if (threadIdx.x < EMB) lds_acc[threadIdx.x] = 0.0f;

    float2 acc = make_float2(0.0f, 0.0f);
    int g = -1;

    if (user < n_users) {
        int s, e;
        if (start) {
            s = start[user];
            e = start[user + 1];
        } else {
            int lo = 0, hi = n_beh;
            while (lo < hi) { int m = (lo + hi) >> 1; if (beh_user[m] < user) lo = m + 1; else hi = m; }
            s = lo;
            hi = n_beh;
            while (lo < hi) { int m = (lo + hi) >> 1; if (beh_user[m] <= user) lo = m + 1; else hi = m; }
            e = lo;
        }

        float2 a0 = make_float2(0.f, 0.f), a1 = a0, a2 = a0, a3 = a0;
        int j = s;
        for (; j + 8 <= e; j += 8) {
            int   b[8];
            float c[8];
            #pragma unroll
            for (int k = 0; k < 8; ++k) { b[k] = beh_item[j + k]; c[k] = beh_cnt[j + k]; }
            float2 v[8];
            #pragma unroll
            for (int k = 0; k < 8; ++k) {
                if (FP16) {
                    __half2 h = *(const __half2*)(item_f16 + (size_t)b[k] * EMB + lane * 2);
                    v[k] = __half22float2(h);
                } else {
                    v[k] = *(const float2*)(item_f32 + (size_t)b[k] * EMB + lane * 2);
                }
            }
            #pragma unroll
            for (int k = 0; k < 8; ++k) {
                float2* a = (k & 3) == 0 ? &a0 : (k & 3) == 1 ? &a1 : (k & 3) == 2 ? &a2 : &a3;
                a->x = fmaf(v[k].x, c[k], a->x);
                a->y = fmaf(v[k].y, c[k], a->y);
            }
        }
        for (; j < e; ++j) {
            int   b = beh_item[j];
            float c = beh_cnt[j];
            float2 v;
            if (FP16) {
                __half2 h = *(const __half2*)(item_f16 + (size_t)b * EMB + lane * 2);
                v = __half22float2(h);
            } else {
                v = *(const float2*)(item_f32 + (size_t)b * EMB + lane * 2);
            }
            a0.x = fmaf(v.x, c, a0.x);
            a0.y = fmaf(v.y, c, a0.y);
        }
        acc.x = (a0.x + a1.x) + (a2.x + a3.x);
        acc.y = (a0.y + a1.y) + (a2.y + a3.y);

        int uid = user_ids[user];
        float2 ue = make_float2(0.f, 0.f);
        if (uid != 0) ue = *(const float2*)(user_table + (size_t)uid * EMB + lane * 2);
        acc.x *= ue.x;
        acc.y *= ue.y;

        g = group_ids[user];
    }

    if (lane == 0) lds_grp[wave] = g;
    __syncthreads();

    int g0 = lds_grp[0];
    bool same = (g0 >= 0) && (lds_grp[1] == g0) && (lds_grp[2] == g0) && (lds_grp[3] == g0);
    if (same) {
        atomicAdd(&lds_acc[lane * 2],     acc.x);
        atomicAdd(&lds_acc[lane * 2 + 1], acc.y);
        __syncthreads();
        if (wave == 0) {
            atomicAdd(&out[(size_t)g0 * EMB + lane * 2],     lds_acc[lane * 2]);
            atomicAdd(&out[(size_t)g0 * EMB + lane * 2 + 1], lds_acc[lane * 2 + 1]);
        }
    } else if (g >= 0) {
        atomicAdd(&out[(size_t)g * EMB + lane * 2],     acc.x);
        atomicAdd(&out[(size_t)g * EMB + lane * 2 + 1], acc.y);
    }
}

extern "C" void kernel_launch(void* const* d_in, const int* in_sizes, int n_in,
                              void* d_out, int out_size, void* d_ws, size_t ws_size,
                              hipStream_t stream) {
    const int*   user_ids   = (const int*)  d_in[0];
    const int*   group_ids  = (const int*)  d_in[1];
    const int*   beh_item   = (const int*)  d_in[2];
    const float* beh_cnt    = (const float*)d_in[3];
    const int*   beh_user   = (const int*)  d_in[4];
    const float* user_table = (const float*)d_in[5];
    const float* item_table = (const float*)d_in[6];

    const int n_users  = in_sizes[0];
    const int n_beh    = in_sizes[2];
    const int item_n   = in_sizes[6] / EMB;

    float* out = (float*)d_out;
    hipMemsetAsync(out, 0, (size_t)out_size * sizeof(float), stream);

    // Workspace layout: [start: (n_users+1) ints][256B-aligned fp16 item table]
    size_t start_bytes = (size_t)(n_users + 1) * sizeof(int);
    size_t f16_off     = (start_bytes + 255) & ~(size_t)255;
    size_t f16_bytes   = (size_t)item_n * EMB * sizeof(__half);

    int*    start    = nullptr;
    __half* item_f16 = nullptr;

    if (ws_size >= start_bytes) {
        start = (int*)d_ws;
        int bblocks = (n_beh + 255) / 256;
        boundary_kernel<<<bblocks, 256, 0, stream>>>(beh_user, start, n_beh, n_users);
    }
    if (ws_size >= f16_off + f16_bytes) {
        item_f16 = (__half*)((char*)d_ws + f16_off);
        int n8 = item_n * EMB / 8;
        convert_kernel<<<(n8 + 255) / 256, 256, 0, stream>>>(item_table, item_f16, n8);
    }

    int ublocks = (n_users + 3) / 4;
    if (item_f16) {
        per_user_kernel<true><<<ublocks, 256, 0, stream>>>(
            user_ids, group_ids, beh_item, beh_cnt, beh_user,
            user_table, item_table, item_f16, start, out, n_users, n_beh);
    } else {
        per_user_kernel<false><<<ublocks, 256, 0, stream>>>(
            user_ids, group_ids, beh_item, beh_cnt, beh_user,
            user_table, item_table, nullptr, start, out, n_users, n_beh);
    }
}